// Round 24
// baseline (147.603 us; speedup 1.0000x reference)
//
#include <hip/hip_runtime.h>

#define N_NODES 20000
#define N_EDGES 320000
#define IN_CH 256
#define HID_CH 512
#define NB_SCAN ((N_NODES + 255) / 256)  // 79

typedef unsigned short u16;
typedef __attribute__((ext_vector_type(4))) float f32x4;
typedef __attribute__((ext_vector_type(8))) short bf16x8;
typedef __attribute__((ext_vector_type(4))) u16 u16x4;
typedef __attribute__((ext_vector_type(8))) u16 u16x8;

__device__ __forceinline__ float bf2f(u16 h) { return __uint_as_float((unsigned)h << 16); }
__device__ __forceinline__ u16 f2bf(float f) {  // round-to-nearest-even
    unsigned u = __float_as_uint(f);
    return (u16)((u + 0x7fffu + ((u >> 16) & 1u)) >> 16);
}

// ---------------------------------------------------------------- fused prep:
// blocks [0,79): zero deg+cursor+flag; [79,79+5000): x f32->bf16; [5079,5175): W transpose
__global__ __launch_bounds__(256) void prep_kernel(
        int* __restrict__ deg, int* __restrict__ cursor, int* __restrict__ flag,
        const float* __restrict__ x, u16* __restrict__ xb,
        const float* __restrict__ W1, u16* __restrict__ hi1,
        const float* __restrict__ W2, u16* __restrict__ hi2) {
    __shared__ float t[64][65];
    int b = blockIdx.x;
    if (b < NB_SCAN) {
        int i = b * 256 + threadIdx.x;
        if (i < N_NODES) { deg[i] = 0; cursor[i] = 0; }
        if (i < NB_SCAN) flag[i] = 0;
        return;
    }
    b -= NB_SCAN;
    const int XB = N_NODES * IN_CH / 4 / 256;  // 5000 (exact)
    if (b < XB) {
        int i = b * 256 + threadIdx.x;  // u16x4 index
        float4 v = ((const float4*)x)[i];
        u16x4 o = {f2bf(v.x), f2bf(v.y), f2bf(v.z), f2bf(v.w)};
        ((u16x4*)xb)[i] = o;
        return;
    }
    b -= XB;
    const float* W;
    u16* hi;
    int K;
    if (b < 32) { W = W1; hi = hi1; K = IN_CH; }
    else        { b -= 32; W = W2; hi = hi2; K = HID_CH; }
    const int N = HID_CH;
    int k0 = (b >> 3) * 64, n0 = (b & 7) * 64;
    int c = threadIdx.x & 63, r4 = threadIdx.x >> 6;
#pragma unroll
    for (int i = 0; i < 16; ++i) {
        int r = i * 4 + r4;
        t[r][c] = W[(size_t)(k0 + r) * N + n0 + c];
    }
    __syncthreads();
#pragma unroll
    for (int i = 0; i < 16; ++i) {
        int n = i * 4 + r4;
        hi[(size_t)(n0 + n) * K + k0 + c] = f2bf(t[c][n]);
    }
}

// ---------------------------------------------------------------- CSR build
__global__ void count_deg_kernel(const int* __restrict__ dst, int* __restrict__ deg, int E) {
    int i = blockIdx.x * blockDim.x + threadIdx.x;
    if (i < E) atomicAdd(&deg[dst[i]], 1);
}

// single-launch scan (replaces scan_pass1 + scan_pass3; R24 isolates this vs R21's bundle):
// each of 79 blocks scans its 256 degs + writes dinv; publishes its aggregate with a
// release flag; lanes t<b acquire-spin on flag[t] IN PARALLEL; LDS-reduce -> base.
// 79 blocks are trivially co-resident (79 << 2048 block slots) -> no deadlock.
__global__ __launch_bounds__(256) void scan_one_kernel(
        const int* __restrict__ deg, float* __restrict__ dinv, int* __restrict__ row_ptr,
        int* __restrict__ agg, int* __restrict__ flag, int N, int E) {
    __shared__ int tmp[256];
    __shared__ int part[256];
    int t = threadIdx.x, b = blockIdx.x;
    int i = b * 256 + t;
    int d = (i < N) ? deg[i] : 0;
    if (i < N) dinv[i] = rsqrtf((float)d + 1.0f);
    tmp[t] = d;
    __syncthreads();
#pragma unroll
    for (int off = 1; off < 256; off <<= 1) {
        int v = (t >= off) ? tmp[t - off] : 0;
        __syncthreads();
        tmp[t] += v;
        __syncthreads();
    }
    if (t == 255) {
        __hip_atomic_store(&agg[b], tmp[255], __ATOMIC_RELAXED, __HIP_MEMORY_SCOPE_AGENT);
        __hip_atomic_store(&flag[b], 1, __ATOMIC_RELEASE, __HIP_MEMORY_SCOPE_AGENT);
    }
    int v = 0;
    if (t < b) {  // b <= 78: parallel waits on all lower blocks
        while (__hip_atomic_load(&flag[t], __ATOMIC_ACQUIRE, __HIP_MEMORY_SCOPE_AGENT) == 0) {
            __builtin_amdgcn_s_sleep(8);
        }
        v = __hip_atomic_load(&agg[t], __ATOMIC_RELAXED, __HIP_MEMORY_SCOPE_AGENT);
    }
    part[t] = v;
    __syncthreads();
#pragma unroll
    for (int off = 128; off > 0; off >>= 1) {
        if (t < off) part[t] += part[t + off];
        __syncthreads();
    }
    int base = part[0];
    if (i < N) row_ptr[i] = base + tmp[t] - d;
    if (i == 0) row_ptr[N] = E;
}

__global__ void scatter_edges_kernel(const int* __restrict__ src, const int* __restrict__ dst,
                                     const int* __restrict__ row_ptr, int* __restrict__ cursor,
                                     const float* __restrict__ dinv, int2* __restrict__ epair,
                                     int E) {
    int e = blockIdx.x * blockDim.x + threadIdx.x;
    if (e >= E) return;
    int d = dst[e];
    int s = src[e];
    int pos = row_ptr[d] + atomicAdd(&cursor[d], 1);
    epair[pos] = make_int2(s, __float_as_int(dinv[s]));
}

// ---------------------------------------------------------------- XCD-sliced gather, group-per-node
// Slice = 64 ch = 2.56 MB table slice (< 4MB XCD L2), pinned to XCD via bid&7 (FETCH
// 177->21 MB verified R8/R12). Wave = 8 groups x 8 lanes; group owns ONE node's slice
// (lane = 8 ch), u16x8 loads 8-deep batched -> no cross-lane reduce.
template <int C, int SLICES>
__global__ __launch_bounds__(256) void gather_agg_kernel(
        const u16* __restrict__ h, const int2* __restrict__ epair,
        const int* __restrict__ row_ptr, const float* __restrict__ dinv,
        u16* __restrict__ z, int N) {
    int bid = blockIdx.x;
    int nb, s;
    if (SLICES == 8) {
        nb = bid >> 3;
        s = bid & 7;
    } else {
        nb = (bid >> 3) * 2 + (bid & 1);
        s = (bid & 7) >> 1;
    }
    int t = threadIdx.x;
    int grp = t >> 3;
    int u = t & 7;
    int n = nb * 32 + grp;
    bool alive = (n < N);
    int nn = alive ? n : (N - 1);
    float dn = dinv[nn];
    const u16* hbase = h + s * 64 + u * 8;
    float acc[8];
    {
        u16x8 ws = *(const u16x8*)(hbase + (size_t)nn * C);
        float sf = dn * dn;
#pragma unroll
        for (int j = 0; j < 8; ++j) acc[j] = bf2f(ws[j]) * sf;
    }
    int e0 = row_ptr[nn];
    int e1 = alive ? row_ptr[nn + 1] : e0;
    int e = e0;
    for (; e + 8 <= e1; e += 8) {
        int2 p[8];
        u16x8 w[8];
#pragma unroll
        for (int b = 0; b < 8; ++b) p[b] = epair[e + b];
#pragma unroll
        for (int b = 0; b < 8; ++b) w[b] = *(const u16x8*)(hbase + (size_t)p[b].x * C);
#pragma unroll
        for (int b = 0; b < 8; ++b) {
            float nr = __int_as_float(p[b].y) * dn;
#pragma unroll
            for (int j = 0; j < 8; ++j) acc[j] = fmaf(bf2f(w[b][j]), nr, acc[j]);
        }
    }
    for (; e + 4 <= e1; e += 4) {
        int2 p0 = epair[e + 0], p1 = epair[e + 1], p2 = epair[e + 2], p3 = epair[e + 3];
        u16x8 w0 = *(const u16x8*)(hbase + (size_t)p0.x * C);
        u16x8 w1 = *(const u16x8*)(hbase + (size_t)p1.x * C);
        u16x8 w2 = *(const u16x8*)(hbase + (size_t)p2.x * C);
        u16x8 w3 = *(const u16x8*)(hbase + (size_t)p3.x * C);
        float n0 = __int_as_float(p0.y) * dn, n1 = __int_as_float(p1.y) * dn;
        float n2 = __int_as_float(p2.y) * dn, n3 = __int_as_float(p3.y) * dn;
#pragma unroll
        for (int j = 0; j < 8; ++j) {
            acc[j] = fmaf(bf2f(w0[j]), n0, acc[j]);
            acc[j] = fmaf(bf2f(w1[j]), n1, acc[j]);
            acc[j] = fmaf(bf2f(w2[j]), n2, acc[j]);
            acc[j] = fmaf(bf2f(w3[j]), n3, acc[j]);
        }
    }
    for (; e < e1; ++e) {
        int2 p = epair[e];
        u16x8 w = *(const u16x8*)(hbase + (size_t)p.x * C);
        float nr = __int_as_float(p.y) * dn;
#pragma unroll
        for (int j = 0; j < 8; ++j) acc[j] = fmaf(bf2f(w[j]), nr, acc[j]);
    }
    if (alive) {
        u16x8 vh;
#pragma unroll
        for (int j = 0; j < 8; ++j) vh[j] = f2bf(acc[j]);
        *(u16x8*)(z + (size_t)n * C + s * 64 + u * 8) = vh;
    }
}

// ---------------------------------------------------------------- 1-term bf16 MFMA GEMM
// C = A_hi @ B_hi + bias (R19/R20-verified numerics: absmax pinned at 3.9e-3 floor).
// Buffer A+B = 16KB x2 = 32KB -> 4 blocks/CU = 32 waves/CU (hardware max).
// 8 waves (2x4 of 64x32), dbuf, 2-barrier counted-vmcnt, swizzle slot ^= (row>>1)&3.
template <int K, bool RELU, bool OUT_BF16>
__global__ __launch_bounds__(512, 8) void gemm_mfma_kernel(
        const u16* __restrict__ A, const u16* __restrict__ Bh,
        const float* __restrict__ bias, void* __restrict__ Cout, int M, int N) {
    __shared__ u16 lds[2][8192];
    const int tid = threadIdx.x;
    const int lane = tid & 63;
    const int wid = tid >> 6;  // 0..7

    // bijective XCD-chunked swizzle (m204)
    const int nmt = (M + 127) / 128;
    const int total = nmt * 4;
    int bid = blockIdx.x;
    int q = total >> 3, r = total & 7;
    int xcd = bid & 7, pp = bid >> 3;
    int lin = (xcd < r) ? (xcd * (q + 1) + pp) : (r * (q + 1) + (xcd - r) * q + pp);
    const int bm = (lin >> 2) * 128;
    const int bn = (lin & 3) * 128;

    const int wm = (wid & 1) * 64;   // 2 wave-rows
    const int wn = (wid >> 1) * 32;  // 4 wave-cols

    f32x4 acc[4][2];
#pragma unroll
    for (int i = 0; i < 4; ++i)
#pragma unroll
        for (int j = 0; j < 2; ++j) acc[i][j] = (f32x4){0.f, 0.f, 0.f, 0.f};

    const int srow = (wid << 4) + (lane >> 2);  // 0..127
    const int scb = (((lane & 3) ^ ((lane >> 3) & 3)) << 4);  // pre-swizzled source col
    const char* srcA  = (const char*)(A  + (size_t)min(bm + srow, M - 1) * K) + scb;
    const char* srcBh = (const char*)(Bh + (size_t)(bn + srow) * K) + scb;
    const int dstoff = wid << 10;  // wave-uniform (HW adds lane*16)

#define GLL(srcp, dstb)                                                                  \
    __builtin_amdgcn_global_load_lds(                                                    \
        (const __attribute__((address_space(1))) void*)(srcp),                           \
        (__attribute__((address_space(3))) void*)((char*)&lds[buf][0] + (dstb)), 16, 0, 0)

#define STAGE(bufv, k0)                                                                  \
    do {                                                                                 \
        int buf = (bufv);                                                                \
        size_t kb2 = (size_t)(k0) * 2;                                                   \
        GLL(srcA + kb2, dstoff);                                                         \
        GLL(srcBh + kb2, 8192 + dstoff);                                                 \
    } while (0)

    STAGE(0, 0);

    const int NT = K / 32;
    const int kb = (lane >> 4) << 4;
#pragma unroll
    for (int t = 0; t < NT; ++t) {
        int cur = t & 1;
        if (t + 1 < NT) {
            STAGE(cur ^ 1, (t + 1) * 32);
            asm volatile("s_waitcnt vmcnt(2)" ::: "memory");
        } else {
            asm volatile("s_waitcnt vmcnt(0)" ::: "memory");
        }
        __builtin_amdgcn_s_barrier();
        asm volatile("" ::: "memory");

        const char* L = (const char*)&lds[cur][0];
        bf16x8 a[4], b_h[2];
#pragma unroll
        for (int i = 0; i < 4; ++i) {
            int ra = wm + i * 16 + (lane & 15);
            int off = ra * 64 + (kb ^ (((ra >> 1) & 3) << 4));
            a[i] = *(const bf16x8*)(L + off);
        }
#pragma unroll
        for (int j = 0; j < 2; ++j) {
            int rb = wn + j * 16 + (lane & 15);
            int off = rb * 64 + (kb ^ (((rb >> 1) & 3) << 4));
            b_h[j] = *(const bf16x8*)(L + 8192 + off);
        }
#pragma unroll
        for (int i = 0; i < 4; ++i)
#pragma unroll
            for (int j = 0; j < 2; ++j)
                acc[i][j] = __builtin_amdgcn_mfma_f32_16x16x32_bf16(a[i], b_h[j], acc[i][j], 0, 0, 0);
        asm volatile("" ::: "memory");
        __builtin_amdgcn_s_barrier();
    }
#undef STAGE
#undef GLL

    // epilogue: C/D layout col=lane&15, row=(lane>>4)*4+t  (m89/m91 verified)
#pragma unroll
    for (int j = 0; j < 2; ++j) {
        int gc = bn + wn + j * 16 + (lane & 15);
        float bv = bias[gc];
#pragma unroll
        for (int i = 0; i < 4; ++i) {
#pragma unroll
            for (int t = 0; t < 4; ++t) {
                int gr = bm + wm + i * 16 + ((lane >> 4) << 2) + t;
                if (gr < M) {
                    float v = acc[i][j][t] + bv;
                    if (RELU) v = fmaxf(v, 0.f);
                    if (OUT_BF16)
                        ((u16*)Cout)[(size_t)gr * N + gc] = f2bf(v);
                    else
                        ((float*)Cout)[(size_t)gr * N + gc] = v;
                }
            }
        }
    }
}

// ---------------------------------------------------------------- launch
extern "C" void kernel_launch(void* const* d_in, const int* in_sizes, int n_in,
                              void* d_out, int out_size, void* d_ws, size_t ws_size,
                              hipStream_t stream) {
    const float* x  = (const float*)d_in[0];
    const int*   ei = (const int*)d_in[1];
    const float* W1 = (const float*)d_in[2];
    const float* b1 = (const float*)d_in[3];
    const float* W2 = (const float*)d_in[4];
    const float* b2 = (const float*)d_in[5];
    const int* src = ei;
    const int* dst = ei + N_EDGES;

    char* ws = (char*)d_ws;
    size_t off = 0;
    auto alloc = [&](size_t bytes) {
        void* p = ws + off;
        off = (off + bytes + 255) & ~(size_t)255;
        return p;
    };
    int*   deg     = (int*)alloc(N_NODES * 4);
    int*   cursor  = (int*)alloc(N_NODES * 4);
    int*   row_ptr = (int*)alloc((N_NODES + 1) * 4);
    float* dinv    = (float*)alloc(N_NODES * 4);
    int*   agg     = (int*)alloc(NB_SCAN * 4);
    int*   flag    = (int*)alloc(NB_SCAN * 4);
    int2*  epair   = (int2*)alloc((size_t)N_EDGES * 8);
    u16*   wt1_hi  = (u16*)alloc((size_t)IN_CH * HID_CH * 2);
    u16*   wt2_hi  = (u16*)alloc((size_t)HID_CH * HID_CH * 2);
    u16*   xb      = (u16*)alloc((size_t)N_NODES * IN_CH * 2);   // [N, 256] bf16
    u16*   z1      = (u16*)alloc((size_t)N_NODES * IN_CH * 2);   // [N, 256] bf16
    u16*   z2      = (u16*)alloc((size_t)N_NODES * HID_CH * 2);  // [N, 512] bf16
    u16*   h1      = (u16*)d_out;  // bf16 h1 scratch in d_out (dead before final GEMM writes)

    // fused prep: zero deg/cursor/flag + x->bf16 + W transpose (hi only)
    const int XB = N_NODES * IN_CH / 4 / 256;  // 5000
    prep_kernel<<<NB_SCAN + XB + 96, 256, 0, stream>>>(deg, cursor, flag, x, xb, W1, wt1_hi,
                                                       W2, wt2_hi);
    // CSR + dinv + epair (single-launch scan, R24 A/B isolation of R21's spin-scan)
    count_deg_kernel<<<(N_EDGES + 255) / 256, 256, 0, stream>>>(dst, deg, N_EDGES);
    scan_one_kernel<<<NB_SCAN, 256, 0, stream>>>(deg, dinv, row_ptr, agg, flag, N_NODES,
                                                 N_EDGES);
    scatter_edges_kernel<<<(N_EDGES + 255) / 256, 256, 0, stream>>>(src, dst, row_ptr, cursor,
                                                                    dinv, epair, N_EDGES);

    const int NMT = (N_NODES + 127) / 128;  // 157 -> grid 628
    const int NB32 = (N_NODES + 31) / 32;   // 625
    // layer 1: z1 = P @ xb (4 slices on XCD pairs) ; h1 = relu(z1 @ W1h + b1) (bf16 out)
    gather_agg_kernel<IN_CH, 4><<<((NB32 + 1) / 2) * 8, 256, 0, stream>>>(
        xb, epair, row_ptr, dinv, z1, N_NODES);
    gemm_mfma_kernel<IN_CH, true, true><<<NMT * 4, 512, 0, stream>>>(z1, wt1_hi, b1, h1,
                                                                     N_NODES, HID_CH);

    // layer 2: z2 = P @ h1 (8 slices, one per XCD) ; out = z2 @ W2h + b2 (fp32 out)
    gather_agg_kernel<HID_CH, 8><<<NB32 * 8, 256, 0, stream>>>(
        h1, epair, row_ptr, dinv, z2, N_NODES);
    gemm_mfma_kernel<HID_CH, false, false><<<NMT * 4, 512, 0, stream>>>(z2, wt2_hi, b2,
                                                                        (float*)d_out, N_NODES,
                                                                        HID_CH);
}

// Round 25
// 144.881 us; speedup vs baseline: 1.0188x; 1.0188x over previous
//
#include <hip/hip_runtime.h>

#define N_NODES 20000
#define N_EDGES 320000
#define IN_CH 256
#define HID_CH 512
#define NB_SCAN ((N_NODES + 255) / 256)  // 79

typedef unsigned short u16;
typedef __attribute__((ext_vector_type(4))) float f32x4;
typedef __attribute__((ext_vector_type(8))) short bf16x8;
typedef __attribute__((ext_vector_type(4))) u16 u16x4;
typedef __attribute__((ext_vector_type(8))) u16 u16x8;

__device__ __forceinline__ float bf2f(u16 h) { return __uint_as_float((unsigned)h << 16); }
__device__ __forceinline__ u16 f2bf(float f) {  // round-to-nearest-even
    unsigned u = __float_as_uint(f);
    return (u16)((u + 0x7fffu + ((u >> 16) & 1u)) >> 16);
}

// ---------------------------------------------------------------- fused prep:
// blocks [0,79): zero deg+cursor; [79,79+5000): x f32->bf16; [5079,5175): W transpose (hi only)
__global__ __launch_bounds__(256) void prep_kernel(
        int* __restrict__ deg, int* __restrict__ cursor,
        const float* __restrict__ x, u16* __restrict__ xb,
        const float* __restrict__ W1, u16* __restrict__ hi1,
        const float* __restrict__ W2, u16* __restrict__ hi2) {
    __shared__ float t[64][65];
    int b = blockIdx.x;
    if (b < NB_SCAN) {
        int i = b * 256 + threadIdx.x;
        if (i < N_NODES) { deg[i] = 0; cursor[i] = 0; }
        return;
    }
    b -= NB_SCAN;
    const int XB = N_NODES * IN_CH / 4 / 256;  // 5000 (exact)
    if (b < XB) {
        int i = b * 256 + threadIdx.x;  // u16x4 index
        float4 v = ((const float4*)x)[i];
        u16x4 o = {f2bf(v.x), f2bf(v.y), f2bf(v.z), f2bf(v.w)};
        ((u16x4*)xb)[i] = o;
        return;
    }
    b -= XB;
    const float* W;
    u16* hi;
    int K;
    if (b < 32) { W = W1; hi = hi1; K = IN_CH; }
    else        { b -= 32; W = W2; hi = hi2; K = HID_CH; }
    const int N = HID_CH;
    int k0 = (b >> 3) * 64, n0 = (b & 7) * 64;
    int c = threadIdx.x & 63, r4 = threadIdx.x >> 6;
#pragma unroll
    for (int i = 0; i < 16; ++i) {
        int r = i * 4 + r4;
        t[r][c] = W[(size_t)(k0 + r) * N + n0 + c];
    }
    __syncthreads();
#pragma unroll
    for (int i = 0; i < 16; ++i) {
        int n = i * 4 + r4;
        hi[(size_t)(n0 + n) * K + k0 + c] = f2bf(t[c][n]);
    }
}

// ---------------------------------------------------------------- CSR build
__global__ void count_deg_kernel(const int* __restrict__ dst, int* __restrict__ deg, int E) {
    int i = blockIdx.x * blockDim.x + threadIdx.x;
    if (i < E) atomicAdd(&deg[dst[i]], 1);
}

__global__ __launch_bounds__(256) void scan_pass1(const int* __restrict__ deg,
                                                  float* __restrict__ dinv,
                                                  int* __restrict__ bsum, int N) {
    __shared__ int tmp[256];
    int t = threadIdx.x;
    int i = blockIdx.x * 256 + t;
    int d = (i < N) ? deg[i] : 0;
    if (i < N) dinv[i] = rsqrtf((float)d + 1.0f);
    tmp[t] = d;
    __syncthreads();
#pragma unroll
    for (int off = 128; off > 0; off >>= 1) {
        if (t < off) tmp[t] += tmp[t + off];
        __syncthreads();
    }
    if (t == 0) bsum[blockIdx.x] = tmp[0];
}

// pass3 with pass2 FUSED: each block re-scans the 79 bsums locally, then block-local scan
__global__ __launch_bounds__(256) void scan_pass3(const int* __restrict__ deg,
                                                  const int* __restrict__ bsum,
                                                  int* __restrict__ row_ptr, int N, int E) {
    __shared__ int tmp[256];
    __shared__ int bs[128];
    int t = threadIdx.x;
    if (t < 128) bs[t] = (t < NB_SCAN) ? bsum[t] : 0;
    __syncthreads();
#pragma unroll
    for (int off = 1; off < 128; off <<= 1) {
        int v = (t >= off && t < 128) ? bs[t - off] : 0;
        __syncthreads();
        if (t < 128) bs[t] += v;
        __syncthreads();
    }
    int base = (blockIdx.x == 0) ? 0 : bs[blockIdx.x - 1];
    int i = blockIdx.x * 256 + t;
    int d = (i < N) ? deg[i] : 0;
    tmp[t] = d;
    __syncthreads();
#pragma unroll
    for (int off = 1; off < 256; off <<= 1) {
        int v = (t >= off) ? tmp[t - off] : 0;
        __syncthreads();
        tmp[t] += v;
        __syncthreads();
    }
    if (i < N) row_ptr[i] = base + tmp[t] - d;
    if (i == 0) row_ptr[N] = E;
}

__global__ void scatter_edges_kernel(const int* __restrict__ src, const int* __restrict__ dst,
                                     const int* __restrict__ row_ptr, int* __restrict__ cursor,
                                     const float* __restrict__ dinv, int2* __restrict__ epair,
                                     int E) {
    int e = blockIdx.x * blockDim.x + threadIdx.x;
    if (e >= E) return;
    int d = dst[e];
    int s = src[e];
    int pos = row_ptr[d] + atomicAdd(&cursor[d], 1);
    epair[pos] = make_int2(s, __float_as_int(dinv[s]));
}

// ---------------------------------------------------------------- XCD-sliced gather, group-per-node
// Slice = 64 ch = 2.56 MB table slice (< 4MB XCD L2), pinned to XCD via bid&7 (FETCH
// 177->21 MB verified R8/R12). Wave = 8 groups x 8 lanes; group owns ONE node's slice
// (lane = 8 ch), u16x8 loads 8-deep batched -> no cross-lane reduce.
template <int C, int SLICES>
__global__ __launch_bounds__(256) void gather_agg_kernel(
        const u16* __restrict__ h, const int2* __restrict__ epair,
        const int* __restrict__ row_ptr, const float* __restrict__ dinv,
        u16* __restrict__ z, int N) {
    int bid = blockIdx.x;
    int nb, s;
    if (SLICES == 8) {
        nb = bid >> 3;
        s = bid & 7;
    } else {
        nb = (bid >> 3) * 2 + (bid & 1);
        s = (bid & 7) >> 1;
    }
    int t = threadIdx.x;
    int grp = t >> 3;
    int u = t & 7;
    int n = nb * 32 + grp;
    bool alive = (n < N);
    int nn = alive ? n : (N - 1);
    float dn = dinv[nn];
    const u16* hbase = h + s * 64 + u * 8;
    float acc[8];
    {
        u16x8 ws = *(const u16x8*)(hbase + (size_t)nn * C);
        float sf = dn * dn;
#pragma unroll
        for (int j = 0; j < 8; ++j) acc[j] = bf2f(ws[j]) * sf;
    }
    int e0 = row_ptr[nn];
    int e1 = alive ? row_ptr[nn + 1] : e0;
    int e = e0;
    for (; e + 8 <= e1; e += 8) {
        int2 p[8];
        u16x8 w[8];
#pragma unroll
        for (int b = 0; b < 8; ++b) p[b] = epair[e + b];
#pragma unroll
        for (int b = 0; b < 8; ++b) w[b] = *(const u16x8*)(hbase + (size_t)p[b].x * C);
#pragma unroll
        for (int b = 0; b < 8; ++b) {
            float nr = __int_as_float(p[b].y) * dn;
#pragma unroll
            for (int j = 0; j < 8; ++j) acc[j] = fmaf(bf2f(w[b][j]), nr, acc[j]);
        }
    }
    for (; e + 4 <= e1; e += 4) {
        int2 p0 = epair[e + 0], p1 = epair[e + 1], p2 = epair[e + 2], p3 = epair[e + 3];
        u16x8 w0 = *(const u16x8*)(hbase + (size_t)p0.x * C);
        u16x8 w1 = *(const u16x8*)(hbase + (size_t)p1.x * C);
        u16x8 w2 = *(const u16x8*)(hbase + (size_t)p2.x * C);
        u16x8 w3 = *(const u16x8*)(hbase + (size_t)p3.x * C);
        float n0 = __int_as_float(p0.y) * dn, n1 = __int_as_float(p1.y) * dn;
        float n2 = __int_as_float(p2.y) * dn, n3 = __int_as_float(p3.y) * dn;
#pragma unroll
        for (int j = 0; j < 8; ++j) {
            acc[j] = fmaf(bf2f(w0[j]), n0, acc[j]);
            acc[j] = fmaf(bf2f(w1[j]), n1, acc[j]);
            acc[j] = fmaf(bf2f(w2[j]), n2, acc[j]);
            acc[j] = fmaf(bf2f(w3[j]), n3, acc[j]);
        }
    }
    for (; e < e1; ++e) {
        int2 p = epair[e];
        u16x8 w = *(const u16x8*)(hbase + (size_t)p.x * C);
        float nr = __int_as_float(p.y) * dn;
#pragma unroll
        for (int j = 0; j < 8; ++j) acc[j] = fmaf(bf2f(w[j]), nr, acc[j]);
    }
    if (alive) {
        u16x8 vh;
#pragma unroll
        for (int j = 0; j < 8; ++j) vh[j] = f2bf(acc[j]);
        *(u16x8*)(z + (size_t)n * C + s * 64 + u * 8) = vh;
    }
}

// ---------------------------------------------------------------- 1-term bf16 MFMA GEMM
// C = A_hi @ B_hi + bias (R19/R20-verified numerics: absmax pinned at 3.9e-3 floor).
// Buffer A+B = 16KB x2 = 32KB -> 4 blocks/CU = 32 waves/CU (hardware max).
// 8 waves (2x4 of 64x32), dbuf, 2-barrier counted-vmcnt, swizzle slot ^= (row>>1)&3.
template <int K, bool RELU, bool OUT_BF16>
__global__ __launch_bounds__(512, 8) void gemm_mfma_kernel(
        const u16* __restrict__ A, const u16* __restrict__ Bh,
        const float* __restrict__ bias, void* __restrict__ Cout, int M, int N) {
    __shared__ u16 lds[2][8192];
    const int tid = threadIdx.x;
    const int lane = tid & 63;
    const int wid = tid >> 6;  // 0..7

    // bijective XCD-chunked swizzle (m204)
    const int nmt = (M + 127) / 128;
    const int total = nmt * 4;
    int bid = blockIdx.x;
    int q = total >> 3, r = total & 7;
    int xcd = bid & 7, pp = bid >> 3;
    int lin = (xcd < r) ? (xcd * (q + 1) + pp) : (r * (q + 1) + (xcd - r) * q + pp);
    const int bm = (lin >> 2) * 128;
    const int bn = (lin & 3) * 128;

    const int wm = (wid & 1) * 64;   // 2 wave-rows
    const int wn = (wid >> 1) * 32;  // 4 wave-cols

    f32x4 acc[4][2];
#pragma unroll
    for (int i = 0; i < 4; ++i)
#pragma unroll
        for (int j = 0; j < 2; ++j) acc[i][j] = (f32x4){0.f, 0.f, 0.f, 0.f};

    const int srow = (wid << 4) + (lane >> 2);  // 0..127
    const int scb = (((lane & 3) ^ ((lane >> 3) & 3)) << 4);  // pre-swizzled source col
    const char* srcA  = (const char*)(A  + (size_t)min(bm + srow, M - 1) * K) + scb;
    const char* srcBh = (const char*)(Bh + (size_t)(bn + srow) * K) + scb;
    const int dstoff = wid << 10;  // wave-uniform (HW adds lane*16)

#define GLL(srcp, dstb)                                                                  \
    __builtin_amdgcn_global_load_lds(                                                    \
        (const __attribute__((address_space(1))) void*)(srcp),                           \
        (__attribute__((address_space(3))) void*)((char*)&lds[buf][0] + (dstb)), 16, 0, 0)

#define STAGE(bufv, k0)                                                                  \
    do {                                                                                 \
        int buf = (bufv);                                                                \
        size_t kb2 = (size_t)(k0) * 2;                                                   \
        GLL(srcA + kb2, dstoff);                                                         \
        GLL(srcBh + kb2, 8192 + dstoff);                                                 \
    } while (0)

    STAGE(0, 0);

    const int NT = K / 32;
    const int kb = (lane >> 4) << 4;
#pragma unroll
    for (int t = 0; t < NT; ++t) {
        int cur = t & 1;
        if (t + 1 < NT) {
            STAGE(cur ^ 1, (t + 1) * 32);
            asm volatile("s_waitcnt vmcnt(2)" ::: "memory");
        } else {
            asm volatile("s_waitcnt vmcnt(0)" ::: "memory");
        }
        __builtin_amdgcn_s_barrier();
        asm volatile("" ::: "memory");

        const char* L = (const char*)&lds[cur][0];
        bf16x8 a[4], b_h[2];
#pragma unroll
        for (int i = 0; i < 4; ++i) {
            int ra = wm + i * 16 + (lane & 15);
            int off = ra * 64 + (kb ^ (((ra >> 1) & 3) << 4));
            a[i] = *(const bf16x8*)(L + off);
        }
#pragma unroll
        for (int j = 0; j < 2; ++j) {
            int rb = wn + j * 16 + (lane & 15);
            int off = rb * 64 + (kb ^ (((rb >> 1) & 3) << 4));
            b_h[j] = *(const bf16x8*)(L + 8192 + off);
        }
#pragma unroll
        for (int i = 0; i < 4; ++i)
#pragma unroll
            for (int j = 0; j < 2; ++j)
                acc[i][j] = __builtin_amdgcn_mfma_f32_16x16x32_bf16(a[i], b_h[j], acc[i][j], 0, 0, 0);
        asm volatile("" ::: "memory");
        __builtin_amdgcn_s_barrier();
    }
#undef STAGE
#undef GLL

    // epilogue: C/D layout col=lane&15, row=(lane>>4)*4+t  (m89/m91 verified)
#pragma unroll
    for (int j = 0; j < 2; ++j) {
        int gc = bn + wn + j * 16 + (lane & 15);
        float bv = bias[gc];
#pragma unroll
        for (int i = 0; i < 4; ++i) {
#pragma unroll
            for (int t = 0; t < 4; ++t) {
                int gr = bm + wm + i * 16 + ((lane >> 4) << 2) + t;
                if (gr < M) {
                    float v = acc[i][j][t] + bv;
                    if (RELU) v = fmaxf(v, 0.f);
                    if (OUT_BF16)
                        ((u16*)Cout)[(size_t)gr * N + gc] = f2bf(v);
                    else
                        ((float*)Cout)[(size_t)gr * N + gc] = v;
                }
            }
        }
    }
}

// ---------------------------------------------------------------- launch
extern "C" void kernel_launch(void* const* d_in, const int* in_sizes, int n_in,
                              void* d_out, int out_size, void* d_ws, size_t ws_size,
                              hipStream_t stream) {
    const float* x  = (const float*)d_in[0];
    const int*   ei = (const int*)d_in[1];
    const float* W1 = (const float*)d_in[2];
    const float* b1 = (const float*)d_in[3];
    const float* W2 = (const float*)d_in[4];
    const float* b2 = (const float*)d_in[5];
    const int* src = ei;
    const int* dst = ei + N_EDGES;

    char* ws = (char*)d_ws;
    size_t off = 0;
    auto alloc = [&](size_t bytes) {
        void* p = ws + off;
        off = (off + bytes + 255) & ~(size_t)255;
        return p;
    };
    int*   deg     = (int*)alloc(N_NODES * 4);
    int*   cursor  = (int*)alloc(N_NODES * 4);
    int*   row_ptr = (int*)alloc((N_NODES + 1) * 4);
    float* dinv    = (float*)alloc(N_NODES * 4);
    int*   bsum    = (int*)alloc(NB_SCAN * 4);
    int2*  epair   = (int2*)alloc((size_t)N_EDGES * 8);
    u16*   wt1_hi  = (u16*)alloc((size_t)IN_CH * HID_CH * 2);
    u16*   wt2_hi  = (u16*)alloc((size_t)HID_CH * HID_CH * 2);
    u16*   xb      = (u16*)alloc((size_t)N_NODES * IN_CH * 2);   // [N, 256] bf16
    u16*   z1      = (u16*)alloc((size_t)N_NODES * IN_CH * 2);   // [N, 256] bf16
    u16*   z2      = (u16*)alloc((size_t)N_NODES * HID_CH * 2);  // [N, 512] bf16
    u16*   h1      = (u16*)d_out;  // bf16 h1 scratch in d_out (dead before final GEMM writes)

    // fused prep: zero deg/cursor + x->bf16 + W transpose (hi only)
    const int XB = N_NODES * IN_CH / 4 / 256;  // 5000
    prep_kernel<<<NB_SCAN + XB + 96, 256, 0, stream>>>(deg, cursor, x, xb, W1, wt1_hi, W2,
                                                       wt2_hi);
    // CSR + dinv + epair
    count_deg_kernel<<<(N_EDGES + 255) / 256, 256, 0, stream>>>(dst, deg, N_EDGES);
    scan_pass1<<<NB_SCAN, 256, 0, stream>>>(deg, dinv, bsum, N_NODES);
    scan_pass3<<<NB_SCAN, 256, 0, stream>>>(deg, bsum, row_ptr, N_NODES, N_EDGES);
    scatter_edges_kernel<<<(N_EDGES + 255) / 256, 256, 0, stream>>>(src, dst, row_ptr, cursor,
                                                                    dinv, epair, N_EDGES);

    const int NMT = (N_NODES + 127) / 128;  // 157 -> grid 628
    const int NB32 = (N_NODES + 31) / 32;   // 625
    // layer 1: z1 = P @ xb (4 slices on XCD pairs) ; h1 = relu(z1 @ W1h + b1) (bf16 out)
    gather_agg_kernel<IN_CH, 4><<<((NB32 + 1) / 2) * 8, 256, 0, stream>>>(
        xb, epair, row_ptr, dinv, z1, N_NODES);
    gemm_mfma_kernel<IN_CH, true, true><<<NMT * 4, 512, 0, stream>>>(z1, wt1_hi, b1, h1,
                                                                     N_NODES, HID_CH);

    // layer 2: z2 = P @ h1 (8 slices, one per XCD) ; out = z2 @ W2h + b2 (fp32 out)
    gather_agg_kernel<HID_CH, 8><<<NB32 * 8, 256, 0, stream>>>(
        h1, epair, row_ptr, dinv, z2, N_NODES);
    gemm_mfma_kernel<HID_CH, false, false><<<NMT * 4, 512, 0, stream>>>(z2, wt2_hi, b2,
                                                                        (float*)d_out, N_NODES,
                                                                        HID_CH);
}